// Round 22
// baseline (265.915 us; speedup 1.0000x reference)
//
#include <hip/hip_runtime.h>
#include <stdint.h>

typedef uint32_t u32;
typedef uint64_t u64;
typedef uint16_t u16;

#define NCLS 81
#define TOPK 200
#define KEEPK 200
#define CONF_THR 0.01f
#define NMS_THR 0.45f
#define NB 32
#define NP 24564
#define NFLAT (NCLS * TOPK)    /* 16200 */
#define NPCHUNK 256
#define NCHUNK ((NP + NPCHUNK - 1) / NPCHUNK) /* 96 */
#define CAP 512
#define NBC (NB * NCLS)        /* 2592 */
#define NGRP (NBC / 4)         /* 648, %8==0 */
#define LCAP 16                /* per (chunk,class) list capacity */
// candidate predicate: fkey(s)>=0xBF7D0000 && s>CONF_THR  <=>  s >= 0.98828125f
#define THRF 0.98828125f

// order-preserving map float -> u32 (ascending)
__device__ __forceinline__ u32 fkey(float f) {
  u32 u = __float_as_uint(f);
  return (u & 0x80000000u) ? ~u : (u | 0x80000000u);
}
__device__ __forceinline__ float unfkey(u32 k) {
  u32 u = (k & 0x80000000u) ? (k & 0x7FFFFFFFu) : ~k;
  return __uint_as_float(u);
}

// ---------------------------------------------------------------------------
// Kernel 0 (v12, proven): block-chunked stream; LDS staging; coalesced flush
// ---------------------------------------------------------------------------
__global__ __launch_bounds__(256) void collect_cands(const float* __restrict__ conf,
                                                     u32* __restrict__ lcnt,
                                                     u64* __restrict__ lcand) {
  __shared__ u32 cnt81[NCLS];
  __shared__ u64 stage[NCLS * LCAP];  // 10368 B

  const int tid = threadIdx.x;
  const int blk = blockIdx.x;
  const int b = blk / NCHUNK, chunk = blk % NCHUNK;
  const int p0 = chunk * NPCHUNK;
  const int cntp = min(NPCHUNK, NP - p0);   // 256 or 244
  const int tot4 = (cntp * NCLS) >> 2;
  const float4* __restrict__ src = (const float4*)(conf + ((size_t)b * NP + p0) * NCLS);

  for (int i = tid; i < NCLS; i += 256) cnt81[i] = 0u;
  __syncthreads();

  auto push = [&](int f, float s) {
    u32 pi = (u32)f / (u32)NCLS;
    u32 c = (u32)f - pi * (u32)NCLS;
    if (c != 0u) {
      u32 sl = atomicAdd(&cnt81[c], 1u);  // LDS atomic
      if (sl < (u32)LCAP) {
        u32 p = (u32)p0 + pi;
        stage[c * LCAP + sl] = ((u64)fkey(s) << 32) | (u32)(~p);
      }
    }
  };
  auto proc = [&](float4 v, int i4) {
    if (v.x >= THRF) push(i4 * 4 + 0, v.x);
    if (v.y >= THRF) push(i4 * 4 + 1, v.y);
    if (v.z >= THRF) push(i4 * 4 + 2, v.z);
    if (v.w >= THRF) push(i4 * 4 + 3, v.w);
  };

  for (int i = tid; i < tot4; i += 512) {
    int i2 = i + 256;
    bool g2 = i2 < tot4;
    float4 v0 = src[i];
    float4 v1;
    if (g2) v1 = src[i2];
    proc(v0, i);
    if (g2) proc(v1, i2);
  }
  __syncthreads();

  u32* gc = lcnt + (size_t)blk * NCLS;
  for (int i = tid; i < NCLS; i += 256) gc[i] = cnt81[i];
  u64* gl = lcand + (size_t)blk * NCLS * LCAP;
  for (int i = tid; i < NCLS * LCAP; i += 256) gl[i] = stage[i];
}

// ---------------------------------------------------------------------------
// Kernel 1a (v15): 4 classes per block; gather + sort + decode only
// ---------------------------------------------------------------------------
__global__ __launch_bounds__(256) void perclass_sel(
    const float* __restrict__ loc, const float* __restrict__ conf,
    const float* __restrict__ prior, const u32* __restrict__ lcnt,
    const u64* __restrict__ lcand, float* __restrict__ bscoreg,
    float* __restrict__ cbox) {
  __shared__ u64 cand4[4][CAP + 17];     // padded to de-alias wave banks
  __shared__ u32 hist[256];
  __shared__ u32 ck4[4][96], offs4[4][96];
  __shared__ u32 sscan[256];
  __shared__ u32 nv[4], flagv[4];
  __shared__ u32 s_sel, s_rem, s_cnt, s_cnt2;

  const int tid = threadIdx.x;
  int i0 = blockIdx.x;
  int grp = (i0 & 7) * (NGRP / 8) + (i0 >> 3);  // bijective XCD swizzle

  if (tid < 4) flagv[tid] = 0u;
  __syncthreads();

  // ---- read 96 chunk counts for each of the 4 classes ----
  for (int t = tid; t < 384; t += 256) {
    int g = t / 96, chunk = t - g * 96;
    int bc = 4 * grp + g;
    int b = bc / NCLS, c = bc - b * NCLS;
    u32 m = 0u;
    if (c != 0) m = lcnt[(size_t)(b * NCHUNK + chunk) * NCLS + c];
    ck4[g][chunk] = m;
    if (m > (u32)LCAP) atomicOr(&flagv[g], 1u);
  }
  __syncthreads();

  // ---- two scan rounds, two classes per round (128 threads each) ----
  for (int r = 0; r < 2; ++r) {
    int g = r * 2 + (tid >> 7);
    int ln = tid & 127;
    sscan[tid] = (ln < 96) ? ck4[g][ln] : 0u;
    __syncthreads();
    for (int d = 1; d < 128; d <<= 1) {
      u32 add = (ln >= d) ? sscan[tid - d] : 0u;
      __syncthreads();
      sscan[tid] += add;
      __syncthreads();
    }
    if (ln < 96) offs4[g][ln] = sscan[tid] - ck4[g][ln];
    if (ln == 95) nv[g] = sscan[tid];
    __syncthreads();
  }

  // ---- zero sort buffers; gather fast classes (fully parallel copy) ----
  for (int i = tid; i < CAP; i += 256) {
    cand4[0][i] = 0ull; cand4[1][i] = 0ull; cand4[2][i] = 0ull; cand4[3][i] = 0ull;
  }
  __syncthreads();
  for (int t = tid; t < 4 * 96 * LCAP; t += 256) {
    int j = t & (LCAP - 1);
    int rest = t >> 4;            // LCAP = 16
    int chunk = rest % 96;
    int g = rest / 96;
    int bc = 4 * grp + g;
    int b = bc / NCLS, c = bc - b * NCLS;
    u32 n = nv[g];
    bool fast = (flagv[g] == 0u) && n >= (u32)TOPK && n <= (u32)CAP && c != 0;
    if (fast && (u32)j < ck4[g][chunk]) {
      const u64* srcl = lcand + ((size_t)(b * NCHUNK + chunk) * NCLS + c) * LCAP;
      cand4[g][offs4[g][chunk] + j] = srcl[j];
    }
  }
  __syncthreads();

  // ---- rare exact fallback per class (uniform branch) ----
  for (int g = 0; g < 4; ++g) {
    int bc = 4 * grp + g;
    int b = bc / NCLS, c = bc - b * NCLS;
    u32 n = nv[g];
    bool fast = (flagv[g] == 0u) && n >= (u32)TOPK && n <= (u32)CAP;
    if (c == 0 || fast) continue;
    const float* confb = conf + (size_t)b * NP * NCLS + c;
    auto loadscore = [&](int p) -> float {
      float s = confb[(size_t)p * NCLS];
      return (s > CONF_THR) ? s : -1.0f;
    };
    u32 pfx = 0, K = TOPK;
    for (int shift = 24; shift >= 0; shift -= 8) {
      hist[tid] = 0; __syncthreads();
      u32 himask = (shift == 24) ? 0u : (0xFFFFFFFFu << (shift + 8));
      for (int p = tid; p < NP; p += 256) {
        u32 kf = fkey(loadscore(p));
        if ((kf & himask) == pfx) atomicAdd(&hist[(kf >> shift) & 255u], 1u);
      }
      __syncthreads();
      if (tid == 0) {
        u32 rem = K;
        int bin = 255;
        for (; bin > 0; --bin) {
          u32 cv = hist[bin];
          if (cv >= rem) break;
          rem -= cv;
        }
        s_sel = (u32)bin; s_rem = rem;
      }
      __syncthreads();
      pfx |= s_sel << shift; K = s_rem;
    }
    const u32 T = pfx;
    const u32 G = TOPK - K;
    cand4[g][tid] = 0ull; cand4[g][tid + 256] = 0ull;
    if (tid == 0) { s_cnt = 0; s_cnt2 = 0; }
    __syncthreads();
    for (int p = tid; p < NP; p += 256) {
      u32 kf = fkey(loadscore(p));
      if (kf > T) {
        u32 slot = atomicAdd(&s_cnt, 1u);
        cand4[g][slot] = ((u64)kf << 32) | (u32)(~(u32)p);
      } else if (kf == T) {
        u32 t2 = atomicAdd(&s_cnt2, 1u);
        u32 slot = G + t2;
        if (slot < (u32)CAP) cand4[g][slot] = ((u64)kf << 32) | (u32)(~(u32)p);
      }
    }
    __syncthreads();
  }

  // ---- interleaved bitonic sort: wave w owns buffer w, 4 pairs/lane ----
  {
    const int w = tid >> 6, ln = tid & 63;
    u64* cd = cand4[w];
    for (u32 k = 2; k <= 512; k <<= 1) {
      for (u32 j = k >> 1; j > 0; j >>= 1) {
        for (int pi = ln; pi < 256; pi += 64) {
          u32 l = (((u32)pi & ~(j - 1)) << 1) | ((u32)pi & (j - 1));
          u32 m = l + j;
          u64 a = cd[l], bb = cd[m];
          if (((l & k) == 0) ? (a < bb) : (a > bb)) { cd[l] = bb; cd[m] = a; }
        }
        __syncthreads();
      }
    }
  }

  // ---- decode: 800 items fully parallel; write boxes+scores to global ----
  for (int t = tid; t < 4 * TOPK; t += 256) {
    int g = t / TOPK, idx = t - g * TOPK;
    int bc = 4 * grp + g;
    int b = bc / NCLS, c = bc - b * NCLS;
    size_t base = (size_t)bc * TOPK + idx;
    if (c == 0) {
      bscoreg[base] = -1.0f;
      float* bp = cbox + base * 4;
      bp[0] = 0.f; bp[1] = 0.f; bp[2] = 0.f; bp[3] = 0.f;
    } else {
      u64 e = cand4[g][idx];
      float myscore = unfkey((u32)(e >> 32));
      int p = (int)(~(u32)e);
      const float* lp = loc + ((size_t)b * NP + p) * 4;
      const float* pp = prior + (size_t)p * 4;
      const float* vp = prior + (size_t)NP * 4 + (size_t)p * 4;
      float p0 = pp[0], p1 = pp[1], p2 = pp[2], p3 = pp[3];
      float pw = p2 - p0, ph = p3 - p1;
      float pcx = (p0 + p2) * 0.5f, pcy = (p1 + p3) * 0.5f;
      float cx = vp[0] * lp[0] * pw + pcx;
      float cy = vp[1] * lp[1] * ph + pcy;
      float ww = expf(vp[2] * lp[2]) * pw;
      float hh = expf(vp[3] * lp[3]) * ph;
      float rx0 = cx - ww * 0.5f, ry0 = cy - hh * 0.5f;
      float rx1 = cx + ww * 0.5f, ry1 = cy + hh * 0.5f;
      bscoreg[base] = myscore;
      float* bp = cbox + base * 4;
      bp[0] = rx0; bp[1] = ry0; bp[2] = rx1; bp[3] = ry1;
    }
  }
}

// ---------------------------------------------------------------------------
// Kernel 1b (v15): standalone ballot NMS, one wave per class
// ---------------------------------------------------------------------------
__global__ __launch_bounds__(64) void nms_kernel(const float* __restrict__ cbox,
                                                 const float* __restrict__ bscoreg,
                                                 float* __restrict__ kept) {
  __shared__ float bx0[TOPK], bx1[TOPK], bx2[TOPK], bx3[TOPK];
  __shared__ float barea[TOPK], bscore[TOPK];

  const int bc = blockIdx.x;
  const int lane = threadIdx.x;
  const size_t base = (size_t)bc * TOPK;

  float sx0[4], sy0[4], sx1[4], sy1[4], sar[4];
#pragma unroll
  for (int s = 0; s < 4; ++s) {
    int cc2 = s * 64 + lane;
    if (cc2 < TOPK) {
      float4 bb = *reinterpret_cast<const float4*>(cbox + (base + cc2) * 4);
      float sc = bscoreg[base + cc2];
      float ar = fmaxf(bb.z - bb.x, 0.f) * fmaxf(bb.w - bb.y, 0.f);
      sx0[s] = bb.x; sy0[s] = bb.y; sx1[s] = bb.z; sy1[s] = bb.w; sar[s] = ar;
      bx0[cc2] = bb.x; bx1[cc2] = bb.y; bx2[cc2] = bb.z; bx3[cc2] = bb.w;
      barea[cc2] = ar; bscore[cc2] = sc;
    } else {
      sx0[s] = 0.f; sy0[s] = 0.f; sx1[s] = 0.f; sy1[s] = 0.f; sar[s] = 0.f;
    }
  }
  __syncthreads();

  u64 sup0 = 0, sup1 = 0, sup2 = 0, sup3 = 0;
  u64 kp0 = 0, kp1 = 0, kp2 = 0, kp3 = 0;

#define IOUBAL(S, OUT) { \
    float xx1 = fmaxf(a0, sx0[S]), yy1 = fmaxf(a1, sy0[S]); \
    float xx2 = fminf(a2, sx1[S]), yy2 = fminf(a3, sy1[S]); \
    float inter = fmaxf(xx2 - xx1, 0.f) * fmaxf(yy2 - yy1, 0.f); \
    float uni = aa + sar[S] - inter; \
    float iou = inter / fmaxf(uni, 1e-10f); \
    OUT = __ballot(iou > NMS_THR); }

#define NMSWORD(SWI, SUPV, KPV, JMAX) \
  for (int j = 0; j < (JMAX); ++j) { \
    int i = (SWI) * 64 + j; \
    float sc_i = bscore[i]; \
    bool kept_i = (sc_i > CONF_THR) && !(((SUPV) >> j) & 1ull); \
    if (kept_i) { \
      (KPV) |= (1ull << j); \
      float a0 = bx0[i], a1 = bx1[i], a2 = bx2[i], a3 = bx3[i]; \
      float aa = barea[i]; \
      u64 bb0, bb1, bb2, bb3; \
      IOUBAL(0, bb0) IOUBAL(1, bb1) IOUBAL(2, bb2) IOUBAL(3, bb3) \
      sup0 |= bb0; sup1 |= bb1; sup2 |= bb2; sup3 |= bb3; \
    } \
  }

  NMSWORD(0, sup0, kp0, 64)
  NMSWORD(1, sup1, kp1, 64)
  NMSWORD(2, sup2, kp2, 64)
  NMSWORD(3, sup3, kp3, TOPK - 192)
#undef NMSWORD
#undef IOUBAL

  {
    int cc2 = 0 * 64 + lane;
    kept[base + cc2] = ((kp0 >> lane) & 1ull) ? bscore[cc2] : 0.f;
  }
  {
    int cc2 = 1 * 64 + lane;
    kept[base + cc2] = ((kp1 >> lane) & 1ull) ? bscore[cc2] : 0.f;
  }
  {
    int cc2 = 2 * 64 + lane;
    kept[base + cc2] = ((kp2 >> lane) & 1ull) ? bscore[cc2] : 0.f;
  }
  {
    int cc2 = 3 * 64 + lane;
    if (cc2 < TOPK)
      kept[base + cc2] = ((kp3 >> lane) & 1ull) ? bscore[cc2] : 0.f;
  }
}

// ---------------------------------------------------------------------------
// Kernel 1 (fallback chain, proven): strided scan version for small ws_size
// ---------------------------------------------------------------------------
__global__ __launch_bounds__(256) void perclass_fallback(
    const float* __restrict__ loc, const float* __restrict__ conf,
    const float* __restrict__ prior, float* __restrict__ kept,
    float* __restrict__ cbox) {
  __shared__ u16 skey[NP];
  __shared__ unsigned int hist[256];
  __shared__ u64 keys[256];
  __shared__ float bx0[TOPK], bx1[TOPK], bx2[TOPK], bx3[TOPK];
  __shared__ float barea[TOPK], bscore[TOPK];
  __shared__ unsigned char sup[TOPK], keepf[TOPK];
  __shared__ unsigned int s_sel, s_rem, s_cnt, s_cnt2;

  const int tid = threadIdx.x;
  const int nwg = NB * NCLS;
  int i0 = blockIdx.x;
  int bc = (i0 & 7) * (nwg / 8) + (i0 >> 3);
  const int b = bc / NCLS, c = bc % NCLS;
  const size_t keptBase = (size_t)bc * TOPK;

  if (c == 0) {
    for (int k = tid; k < TOPK; k += 256) {
      kept[keptBase + k] = 0.f;
      float* bp = cbox + (keptBase + k) * 4;
      bp[0] = 0.f; bp[1] = 0.f; bp[2] = 0.f; bp[3] = 0.f;
    }
    return;
  }

  const float* confb = conf + (size_t)b * NP * NCLS + c;
  auto loadscore = [&](int p) -> float {
    float s = confb[(size_t)p * NCLS];
    return (s > CONF_THR) ? s : -1.0f;
  };

  for (int p = tid; p < NP; p += 256)
    skey[p] = (u16)(fkey(loadscore(p)) >> 16);
  __syncthreads();

  auto select_bin = [&](u32 Kin) {
    if (tid == 0) {
      u32 rem = Kin;
      int bin = 255;
      for (; bin > 0; --bin) {
        u32 cnt = hist[bin];
        if (cnt >= rem) break;
        rem -= cnt;
      }
      s_sel = (u32)bin; s_rem = rem;
    }
    __syncthreads();
  };

  const u32 NEGK16 = 0x407Fu;
  u32 K = TOPK;
  hist[tid] = 0; __syncthreads();
  for (int p = tid; p < NP; p += 256) atomicAdd(&hist[skey[p] >> 8], 1u);
  __syncthreads();
  select_bin(K);
  u32 pfx16 = s_sel << 8; K = s_rem;

  hist[tid] = 0; __syncthreads();
  {
    u32 hb = pfx16 >> 8;
    for (int p = tid; p < NP; p += 256) {
      u16 v = skey[p];
      if ((u32)(v >> 8) == hb) atomicAdd(&hist[v & 255], 1u);
    }
  }
  __syncthreads();
  select_bin(K);
  pfx16 |= s_sel; K = s_rem;

  const bool fillMode = (pfx16 == NEGK16);
  u32 T;
  if (!fillMode) {
    u32 pfull = pfx16 << 16;
    hist[tid] = 0; __syncthreads();
    for (int p = tid; p < NP; p += 256) {
      if ((u32)skey[p] == pfx16) {
        u32 kf = fkey(loadscore(p));
        atomicAdd(&hist[(kf >> 8) & 255], 1u);
      }
    }
    __syncthreads();
    select_bin(K);
    pfull |= s_sel << 8; K = s_rem;

    hist[tid] = 0; __syncthreads();
    for (int p = tid; p < NP; p += 256) {
      if ((u32)skey[p] == pfx16) {
        u32 kf = fkey(loadscore(p));
        if ((kf >> 8) == (pfull >> 8)) atomicAdd(&hist[kf & 255], 1u);
      }
    }
    __syncthreads();
    select_bin(K);
    T = pfull | s_sel; K = s_rem;
  } else {
    T = 0x407FFFFFu;
  }

  const u32 G = TOPK - K;
  keys[tid] = 0;
  if (tid == 0) { s_cnt = 0; s_cnt2 = 0; }
  __syncthreads();
  for (int p = tid; p < NP; p += 256) {
    u32 v = skey[p];
    if (v > pfx16) {
      float s = loadscore(p);
      u32 slot = atomicAdd(&s_cnt, 1u);
      keys[slot] = ((u64)fkey(s) << 32) | (u32)(~(u32)p);
    } else if (!fillMode && v == pfx16) {
      float s = loadscore(p);
      u32 kf = fkey(s);
      if (kf > T) {
        u32 slot = atomicAdd(&s_cnt, 1u);
        keys[slot] = ((u64)kf << 32) | (u32)(~(u32)p);
      } else if (kf == T) {
        u32 t2 = atomicAdd(&s_cnt2, 1u);
        u32 slot = G + t2;
        if (slot < 256u) keys[slot] = ((u64)kf << 32) | (u32)(~(u32)p);
      }
    }
  }
  __syncthreads();
  if (fillMode) {
    for (int k = (int)G + tid; k < TOPK; k += 256)
      keys[k] = ((u64)T << 32) | 0xFFFFFFFFull;
  }
  __syncthreads();

  for (u32 kk = 2; kk <= 256; kk <<= 1) {
    for (u32 j = kk >> 1; j > 0; j >>= 1) {
      u32 ixj = (u32)tid ^ j;
      if (ixj > (u32)tid) {
        u64 a = keys[tid], bb = keys[ixj];
        bool asc = (tid & kk) != 0;
        if (asc ? (a > bb) : (a < bb)) { keys[tid] = bb; keys[ixj] = a; }
      }
      __syncthreads();
    }
  }

  if (tid < TOPK) {
    u64 e = keys[tid];
    float s = unfkey((u32)(e >> 32));
    int p = (int)(~(u32)e);
    const float* lp = loc + ((size_t)b * NP + p) * 4;
    const float* pp = prior + (size_t)p * 4;
    const float* vp = prior + (size_t)NP * 4 + (size_t)p * 4;
    float p0 = pp[0], p1 = pp[1], p2 = pp[2], p3 = pp[3];
    float pw = p2 - p0, ph = p3 - p1;
    float pcx = (p0 + p2) * 0.5f, pcy = (p1 + p3) * 0.5f;
    float cx = vp[0] * lp[0] * pw + pcx;
    float cy = vp[1] * lp[1] * ph + pcy;
    float w = expf(vp[2] * lp[2]) * pw;
    float h = expf(vp[3] * lp[3]) * ph;
    float x0 = cx - w * 0.5f, y0 = cy - h * 0.5f;
    float x1 = cx + w * 0.5f, y1 = cy + h * 0.5f;
    bx0[tid] = x0; bx1[tid] = y0; bx2[tid] = x1; bx3[tid] = y1;
    barea[tid] = fmaxf(x1 - x0, 0.f) * fmaxf(y1 - y0, 0.f);
    bscore[tid] = s;
    sup[tid] = 0;
    keepf[tid] = 0;
  }
  __syncthreads();

  for (int i = 0; i < TOPK; ++i) {
    bool kept_i = (bscore[i] > CONF_THR) && (sup[i] == 0);
    __syncthreads();
    if (kept_i) {
      if (tid < TOPK) {
        float xx1 = fmaxf(bx0[i], bx0[tid]);
        float yy1 = fmaxf(bx1[i], bx1[tid]);
        float xx2 = fminf(bx2[i], bx2[tid]);
        float yy2 = fminf(bx3[i], bx3[tid]);
        float inter = fmaxf(xx2 - xx1, 0.f) * fmaxf(yy2 - yy1, 0.f);
        float uni = barea[i] + barea[tid] - inter;
        float iou = inter / fmaxf(uni, 1e-10f);
        if (iou > NMS_THR) sup[tid] = 1;
      }
      if (tid == 0) keepf[i] = 1;
    }
    __syncthreads();
  }

  if (tid < TOPK) {
    kept[keptBase + tid] = keepf[tid] ? bscore[tid] : 0.f;
    float* bp = cbox + (keptBase + tid) * 4;
    bp[0] = bx0[tid]; bp[1] = bx1[tid]; bp[2] = bx2[tid]; bp[3] = bx3[tid];
  }
}

// ---------------------------------------------------------------------------
// Kernel 2: per-batch top-200 with parallel select + skewed hist
// ---------------------------------------------------------------------------
__global__ __launch_bounds__(256) void final_topk(
    const float* __restrict__ kept, const float* __restrict__ cbox,
    float* __restrict__ out) {
  __shared__ u32 histm[4 * 257];
  __shared__ u32 ssuf[256];
  __shared__ u64 keys[256];
  __shared__ u32 s_sel, s_rem, s_cnt, s_cnt2;

  const int tid = threadIdx.x;
  const int b = blockIdx.x;
  const float* sc = kept + (size_t)b * NFLAT;
  const int sub4 = (tid & 3) * 257;

  auto select256s = [&](u32 Kin) {
    __syncthreads();
    u32 cntv = histm[tid] + histm[257 + tid] + histm[514 + tid] + histm[771 + tid];
    ssuf[tid] = cntv;
    __syncthreads();
    for (int d = 1; d < 256; d <<= 1) {
      u32 add = (tid + d < 256) ? ssuf[tid + d] : 0u;
      __syncthreads();
      ssuf[tid] += add;
      __syncthreads();
    }
    u32 s = ssuf[tid], above = s - cntv;
    if (s >= Kin && above < Kin) { s_sel = (u32)tid; s_rem = Kin - above; }
    __syncthreads();
  };

  u32 pfx = 0;
  u32 K = KEEPK;
  for (int shift = 24; shift >= 0; shift -= 8) {
    for (int j = tid; j < 4 * 257; j += 256) histm[j] = 0u;
    __syncthreads();
    u32 himask = (shift == 24) ? 0u : (0xFFFFFFFFu << (shift + 8));
    for (int p = tid; p < NFLAT; p += 256) {
      u32 kf = fkey(sc[p]);
      if ((kf & himask) == pfx) atomicAdd(&histm[sub4 + ((kf >> shift) & 255u)], 1u);
    }
    select256s(K);
    pfx |= s_sel << shift; K = s_rem;
  }

  const bool fill2 = (pfx == fkey(0.0f));
  const u32 G = KEEPK - K;
  keys[tid] = 0;
  if (tid == 0) { s_cnt = 0; s_cnt2 = 0; }
  __syncthreads();
  for (int p = tid; p < NFLAT; p += 256) {
    u32 kf = fkey(sc[p]);
    if (kf > pfx) {
      u32 slot = atomicAdd(&s_cnt, 1u);
      keys[slot] = ((u64)kf << 32) | (u32)(~(u32)p);
    } else if (!fill2 && kf == pfx) {
      u32 t2 = atomicAdd(&s_cnt2, 1u);
      u32 slot = G + t2;
      if (slot < 256u) keys[slot] = ((u64)kf << 32) | (u32)(~(u32)p);
    }
  }
  __syncthreads();
  if (fill2) {
    for (int k = (int)G + tid; k < KEEPK; k += 256)
      keys[k] = ((u64)pfx << 32) | 0xFFFFFFFFull;
  }
  __syncthreads();

  for (u32 kk = 2; kk <= 256; kk <<= 1) {
    for (u32 j = kk >> 1; j > 0; j >>= 1) {
      u32 ixj = (u32)tid ^ j;
      if (ixj > (u32)tid) {
        u64 a = keys[tid], bb = keys[ixj];
        bool asc = (tid & kk) != 0;
        if (asc ? (a > bb) : (a < bb)) { keys[tid] = bb; keys[ixj] = a; }
      }
      __syncthreads();
    }
  }

  if (tid < KEEPK) {
    u64 e = keys[tid];
    float s = unfkey((u32)(e >> 32));
    u32 fi = ~(u32)e;
    float r0 = 0.f, r1 = 0.f, r2 = 0.f, r3 = 0.f, r4 = 0.f, r5 = 0.f, r6 = 0.f;
    if (s > 0.f) {
      r0 = (float)b;
      r1 = (float)(fi / TOPK);
      r2 = s;
      const float* bp = cbox + ((size_t)b * NFLAT + fi) * 4;
      r3 = bp[0]; r4 = bp[1]; r5 = bp[2]; r6 = bp[3];
    }
    float* op = out + ((size_t)b * KEEPK + tid) * 7;
    op[0] = r0; op[1] = r1; op[2] = r2; op[3] = r3;
    op[4] = r4; op[5] = r5; op[6] = r6;
  }
}

extern "C" void kernel_launch(void* const* d_in, const int* in_sizes, int n_in,
                              void* d_out, int out_size, void* d_ws, size_t ws_size,
                              hipStream_t stream) {
  const float* loc = (const float*)d_in[0];
  const float* conf = (const float*)d_in[1];
  const float* prior = (const float*)d_in[2];
  float* out = (float*)d_out;

  float* kept = (float*)d_ws;                     // NBC*TOPK floats
  float* cbox = kept + (size_t)NBC * TOPK;        // NBC*TOPK*4 floats
  const size_t baseBytes = (size_t)NBC * TOPK * 5 * sizeof(float);       // 10.37 MB
  const size_t lcntBytes = (size_t)NB * NCHUNK * NCLS * sizeof(u32);     // 0.995 MB
  const size_t lcandBytes = (size_t)NB * NCHUNK * NCLS * LCAP * sizeof(u64); // 31.85 MB
  const size_t bscBytes = (size_t)NBC * TOPK * sizeof(float);            // 2.07 MB

  if (ws_size >= baseBytes + lcntBytes + lcandBytes + bscBytes) {
    u32* lcnt = (u32*)((char*)d_ws + baseBytes);
    u64* lcand = (u64*)((char*)d_ws + baseBytes + lcntBytes);
    float* bscoreg = (float*)((char*)d_ws + baseBytes + lcntBytes + lcandBytes);
    collect_cands<<<dim3(NB * NCHUNK), dim3(256), 0, stream>>>(conf, lcnt, lcand);
    perclass_sel<<<dim3(NGRP), dim3(256), 0, stream>>>(loc, conf, prior, lcnt,
                                                       lcand, bscoreg, cbox);
    nms_kernel<<<dim3(NBC), dim3(64), 0, stream>>>(cbox, bscoreg, kept);
  } else {
    perclass_fallback<<<dim3(NBC), dim3(256), 0, stream>>>(loc, conf, prior,
                                                           kept, cbox);
  }
  final_topk<<<dim3(NB), dim3(256), 0, stream>>>(kept, cbox, out);
}

// Round 23
// 258.213 us; speedup vs baseline: 1.0298x; 1.0298x over previous
//
#include <hip/hip_runtime.h>
#include <stdint.h>

typedef uint32_t u32;
typedef uint64_t u64;
typedef uint16_t u16;

#define NCLS 81
#define TOPK 200
#define KEEPK 200
#define CONF_THR 0.01f
#define NMS_THR 0.45f
#define NB 32
#define NP 24564
#define NFLAT (NCLS * TOPK)    /* 16200 */
#define NPCHUNK 256
#define NCHUNK ((NP + NPCHUNK - 1) / NPCHUNK) /* 96 */
#define CAP 512
#define NBC (NB * NCLS)        /* 2592 */
#define NGRP (NBC / 4)         /* 648, %8==0 */
#define LCAP 16                /* per (chunk,class) list capacity */
// candidate predicate: fkey(s)>=0xBF7D0000 && s>CONF_THR  <=>  s >= 0.98828125f
#define THRF 0.98828125f

// order-preserving map float -> u32 (ascending)
__device__ __forceinline__ u32 fkey(float f) {
  u32 u = __float_as_uint(f);
  return (u & 0x80000000u) ? ~u : (u | 0x80000000u);
}
__device__ __forceinline__ float unfkey(u32 k) {
  u32 u = (k & 0x80000000u) ? (k & 0x7FFFFFFFu) : ~k;
  return __uint_as_float(u);
}

// ---------------------------------------------------------------------------
// Kernel 0 (v16): block-chunked stream, ILP-4, LDS staging, coalesced flush
// ---------------------------------------------------------------------------
__global__ __launch_bounds__(256) void collect_cands(const float* __restrict__ conf,
                                                     u32* __restrict__ lcnt,
                                                     u64* __restrict__ lcand) {
  __shared__ u32 cnt81[NCLS];
  __shared__ u64 stage[NCLS * LCAP];  // 10368 B

  const int tid = threadIdx.x;
  const int blk = blockIdx.x;
  const int b = blk / NCHUNK, chunk = blk % NCHUNK;
  const int p0 = chunk * NPCHUNK;
  const int cntp = min(NPCHUNK, NP - p0);   // 256 or 244
  const int tot4 = (cntp * NCLS) >> 2;
  const float4* __restrict__ src = (const float4*)(conf + ((size_t)b * NP + p0) * NCLS);

  for (int i = tid; i < NCLS; i += 256) cnt81[i] = 0u;
  __syncthreads();

  auto push = [&](int f, float s) {
    u32 pi = (u32)f / (u32)NCLS;
    u32 c = (u32)f - pi * (u32)NCLS;
    if (c != 0u) {
      u32 sl = atomicAdd(&cnt81[c], 1u);  // LDS atomic
      if (sl < (u32)LCAP) {
        u32 p = (u32)p0 + pi;
        stage[c * LCAP + sl] = ((u64)fkey(s) << 32) | (u32)(~p);
      }
    }
  };
  auto proc = [&](float4 v, int i4) {
    if (v.x >= THRF) push(i4 * 4 + 0, v.x);
    if (v.y >= THRF) push(i4 * 4 + 1, v.y);
    if (v.z >= THRF) push(i4 * 4 + 2, v.z);
    if (v.w >= THRF) push(i4 * 4 + 3, v.w);
  };

  for (int i = tid; i < tot4; i += 1024) {
    int i1 = i + 256, i2 = i + 512, i3 = i + 768;
    bool g1 = i1 < tot4, g2 = i2 < tot4, g3 = i3 < tot4;
    float4 v0 = src[i];
    float4 v1, v2, v3;
    if (g1) v1 = src[i1];
    if (g2) v2 = src[i2];
    if (g3) v3 = src[i3];
    proc(v0, i);
    if (g1) proc(v1, i1);
    if (g2) proc(v2, i2);
    if (g3) proc(v3, i3);
  }
  __syncthreads();

  u32* gc = lcnt + (size_t)blk * NCLS;
  for (int i = tid; i < NCLS; i += 256) gc[i] = cnt81[i];
  u64* gl = lcand + (size_t)blk * NCLS * LCAP;
  for (int i = tid; i < NCLS * LCAP; i += 256) gl[i] = stage[i];
}

// ---------------------------------------------------------------------------
// Kernel 1a (v16): 4 classes per block; gather + barrier-free sort + decode
// ---------------------------------------------------------------------------
__global__ __launch_bounds__(256) void perclass_sel(
    const float* __restrict__ loc, const float* __restrict__ conf,
    const float* __restrict__ prior, const u32* __restrict__ lcnt,
    const u64* __restrict__ lcand, float* __restrict__ bscoreg,
    float* __restrict__ cbox) {
  __shared__ u64 cand4[4][CAP + 17];     // padded to de-alias wave banks
  __shared__ u32 hist[256];
  __shared__ u32 ck4[4][96], offs4[4][96];
  __shared__ u32 sscan[256];
  __shared__ u32 nv[4], flagv[4];
  __shared__ u32 s_sel, s_rem, s_cnt, s_cnt2;

  const int tid = threadIdx.x;
  int i0 = blockIdx.x;
  int grp = (i0 & 7) * (NGRP / 8) + (i0 >> 3);  // bijective XCD swizzle

  if (tid < 4) flagv[tid] = 0u;
  __syncthreads();

  // ---- read 96 chunk counts for each of the 4 classes ----
  for (int t = tid; t < 384; t += 256) {
    int g = t / 96, chunk = t - g * 96;
    int bc = 4 * grp + g;
    int b = bc / NCLS, c = bc - b * NCLS;
    u32 m = 0u;
    if (c != 0) m = lcnt[(size_t)(b * NCHUNK + chunk) * NCLS + c];
    ck4[g][chunk] = m;
    if (m > (u32)LCAP) atomicOr(&flagv[g], 1u);
  }
  __syncthreads();

  // ---- two scan rounds, two classes per round (128 threads each) ----
  for (int r = 0; r < 2; ++r) {
    int g = r * 2 + (tid >> 7);
    int ln = tid & 127;
    sscan[tid] = (ln < 96) ? ck4[g][ln] : 0u;
    __syncthreads();
    for (int d = 1; d < 128; d <<= 1) {
      u32 add = (ln >= d) ? sscan[tid - d] : 0u;
      __syncthreads();
      sscan[tid] += add;
      __syncthreads();
    }
    if (ln < 96) offs4[g][ln] = sscan[tid] - ck4[g][ln];
    if (ln == 95) nv[g] = sscan[tid];
    __syncthreads();
  }

  // ---- zero sort buffers; gather fast classes (fully parallel copy) ----
  for (int i = tid; i < CAP; i += 256) {
    cand4[0][i] = 0ull; cand4[1][i] = 0ull; cand4[2][i] = 0ull; cand4[3][i] = 0ull;
  }
  __syncthreads();
  for (int t = tid; t < 4 * 96 * LCAP; t += 256) {
    int j = t & (LCAP - 1);
    int rest = t >> 4;            // LCAP = 16
    int chunk = rest % 96;
    int g = rest / 96;
    int bc = 4 * grp + g;
    int b = bc / NCLS, c = bc - b * NCLS;
    u32 n = nv[g];
    bool fast = (flagv[g] == 0u) && n >= (u32)TOPK && n <= (u32)CAP && c != 0;
    if (fast && (u32)j < ck4[g][chunk]) {
      const u64* srcl = lcand + ((size_t)(b * NCHUNK + chunk) * NCLS + c) * LCAP;
      cand4[g][offs4[g][chunk] + j] = srcl[j];
    }
  }
  __syncthreads();

  // ---- rare exact fallback per class (uniform branch) ----
  for (int g = 0; g < 4; ++g) {
    int bc = 4 * grp + g;
    int b = bc / NCLS, c = bc - b * NCLS;
    u32 n = nv[g];
    bool fast = (flagv[g] == 0u) && n >= (u32)TOPK && n <= (u32)CAP;
    if (c == 0 || fast) continue;
    const float* confb = conf + (size_t)b * NP * NCLS + c;
    auto loadscore = [&](int p) -> float {
      float s = confb[(size_t)p * NCLS];
      return (s > CONF_THR) ? s : -1.0f;
    };
    u32 pfx = 0, K = TOPK;
    for (int shift = 24; shift >= 0; shift -= 8) {
      hist[tid] = 0; __syncthreads();
      u32 himask = (shift == 24) ? 0u : (0xFFFFFFFFu << (shift + 8));
      for (int p = tid; p < NP; p += 256) {
        u32 kf = fkey(loadscore(p));
        if ((kf & himask) == pfx) atomicAdd(&hist[(kf >> shift) & 255u], 1u);
      }
      __syncthreads();
      if (tid == 0) {
        u32 rem = K;
        int bin = 255;
        for (; bin > 0; --bin) {
          u32 cv = hist[bin];
          if (cv >= rem) break;
          rem -= cv;
        }
        s_sel = (u32)bin; s_rem = rem;
      }
      __syncthreads();
      pfx |= s_sel << shift; K = s_rem;
    }
    const u32 T = pfx;
    const u32 G = TOPK - K;
    cand4[g][tid] = 0ull; cand4[g][tid + 256] = 0ull;
    if (tid == 0) { s_cnt = 0; s_cnt2 = 0; }
    __syncthreads();
    for (int p = tid; p < NP; p += 256) {
      u32 kf = fkey(loadscore(p));
      if (kf > T) {
        u32 slot = atomicAdd(&s_cnt, 1u);
        cand4[g][slot] = ((u64)kf << 32) | (u32)(~(u32)p);
      } else if (kf == T) {
        u32 t2 = atomicAdd(&s_cnt2, 1u);
        u32 slot = G + t2;
        if (slot < (u32)CAP) cand4[g][slot] = ((u64)kf << 32) | (u32)(~(u32)p);
      }
    }
    __syncthreads();
  }

  // ---- interleaved bitonic sort: wave w owns buffer w exclusively, so NO
  //      block barriers needed inside (within-wave DS ordering suffices) ----
  {
    const int w = tid >> 6, ln = tid & 63;
    u64* cd = cand4[w];
    for (u32 k = 2; k <= 512; k <<= 1) {
      for (u32 j = k >> 1; j > 0; j >>= 1) {
#pragma unroll
        for (int q = 0; q < 4; ++q) {
          int pi = ln + q * 64;
          u32 l = (((u32)pi & ~(j - 1)) << 1) | ((u32)pi & (j - 1));
          u32 m = l + j;
          u64 a = cd[l], bb = cd[m];
          if (((l & k) == 0) ? (a < bb) : (a > bb)) { cd[l] = bb; cd[m] = a; }
        }
      }
    }
  }
  __syncthreads();  // single barrier before cross-wave decode

  // ---- decode: 800 items fully parallel; write boxes+scores to global ----
  for (int t = tid; t < 4 * TOPK; t += 256) {
    int g = t / TOPK, idx = t - g * TOPK;
    int bc = 4 * grp + g;
    int b = bc / NCLS, c = bc - b * NCLS;
    size_t base = (size_t)bc * TOPK + idx;
    if (c == 0) {
      bscoreg[base] = -1.0f;
      float* bp = cbox + base * 4;
      bp[0] = 0.f; bp[1] = 0.f; bp[2] = 0.f; bp[3] = 0.f;
    } else {
      u64 e = cand4[g][idx];
      float myscore = unfkey((u32)(e >> 32));
      int p = (int)(~(u32)e);
      const float* lp = loc + ((size_t)b * NP + p) * 4;
      const float* pp = prior + (size_t)p * 4;
      const float* vp = prior + (size_t)NP * 4 + (size_t)p * 4;
      float p0 = pp[0], p1 = pp[1], p2 = pp[2], p3 = pp[3];
      float pw = p2 - p0, ph = p3 - p1;
      float pcx = (p0 + p2) * 0.5f, pcy = (p1 + p3) * 0.5f;
      float cx = vp[0] * lp[0] * pw + pcx;
      float cy = vp[1] * lp[1] * ph + pcy;
      float ww = expf(vp[2] * lp[2]) * pw;
      float hh = expf(vp[3] * lp[3]) * ph;
      float rx0 = cx - ww * 0.5f, ry0 = cy - hh * 0.5f;
      float rx1 = cx + ww * 0.5f, ry1 = cy + hh * 0.5f;
      bscoreg[base] = myscore;
      float* bp = cbox + base * 4;
      bp[0] = rx0; bp[1] = ry0; bp[2] = rx1; bp[3] = ry1;
    }
  }
}

// ---------------------------------------------------------------------------
// Kernel 1b (v15, proven): standalone ballot NMS, one wave per class
// ---------------------------------------------------------------------------
__global__ __launch_bounds__(64) void nms_kernel(const float* __restrict__ cbox,
                                                 const float* __restrict__ bscoreg,
                                                 float* __restrict__ kept) {
  __shared__ float bx0[TOPK], bx1[TOPK], bx2[TOPK], bx3[TOPK];
  __shared__ float barea[TOPK], bscore[TOPK];

  const int bc = blockIdx.x;
  const int lane = threadIdx.x;
  const size_t base = (size_t)bc * TOPK;

  float sx0[4], sy0[4], sx1[4], sy1[4], sar[4];
#pragma unroll
  for (int s = 0; s < 4; ++s) {
    int cc2 = s * 64 + lane;
    if (cc2 < TOPK) {
      float4 bb = *reinterpret_cast<const float4*>(cbox + (base + cc2) * 4);
      float sc = bscoreg[base + cc2];
      float ar = fmaxf(bb.z - bb.x, 0.f) * fmaxf(bb.w - bb.y, 0.f);
      sx0[s] = bb.x; sy0[s] = bb.y; sx1[s] = bb.z; sy1[s] = bb.w; sar[s] = ar;
      bx0[cc2] = bb.x; bx1[cc2] = bb.y; bx2[cc2] = bb.z; bx3[cc2] = bb.w;
      barea[cc2] = ar; bscore[cc2] = sc;
    } else {
      sx0[s] = 0.f; sy0[s] = 0.f; sx1[s] = 0.f; sy1[s] = 0.f; sar[s] = 0.f;
    }
  }
  __syncthreads();

  u64 sup0 = 0, sup1 = 0, sup2 = 0, sup3 = 0;
  u64 kp0 = 0, kp1 = 0, kp2 = 0, kp3 = 0;

#define IOUBAL(S, OUT) { \
    float xx1 = fmaxf(a0, sx0[S]), yy1 = fmaxf(a1, sy0[S]); \
    float xx2 = fminf(a2, sx1[S]), yy2 = fminf(a3, sy1[S]); \
    float inter = fmaxf(xx2 - xx1, 0.f) * fmaxf(yy2 - yy1, 0.f); \
    float uni = aa + sar[S] - inter; \
    float iou = inter / fmaxf(uni, 1e-10f); \
    OUT = __ballot(iou > NMS_THR); }

#define NMSWORD(SWI, SUPV, KPV, JMAX) \
  for (int j = 0; j < (JMAX); ++j) { \
    int i = (SWI) * 64 + j; \
    float sc_i = bscore[i]; \
    bool kept_i = (sc_i > CONF_THR) && !(((SUPV) >> j) & 1ull); \
    if (kept_i) { \
      (KPV) |= (1ull << j); \
      float a0 = bx0[i], a1 = bx1[i], a2 = bx2[i], a3 = bx3[i]; \
      float aa = barea[i]; \
      u64 bb0, bb1, bb2, bb3; \
      IOUBAL(0, bb0) IOUBAL(1, bb1) IOUBAL(2, bb2) IOUBAL(3, bb3) \
      sup0 |= bb0; sup1 |= bb1; sup2 |= bb2; sup3 |= bb3; \
    } \
  }

  NMSWORD(0, sup0, kp0, 64)
  NMSWORD(1, sup1, kp1, 64)
  NMSWORD(2, sup2, kp2, 64)
  NMSWORD(3, sup3, kp3, TOPK - 192)
#undef NMSWORD
#undef IOUBAL

  {
    int cc2 = 0 * 64 + lane;
    kept[base + cc2] = ((kp0 >> lane) & 1ull) ? bscore[cc2] : 0.f;
  }
  {
    int cc2 = 1 * 64 + lane;
    kept[base + cc2] = ((kp1 >> lane) & 1ull) ? bscore[cc2] : 0.f;
  }
  {
    int cc2 = 2 * 64 + lane;
    kept[base + cc2] = ((kp2 >> lane) & 1ull) ? bscore[cc2] : 0.f;
  }
  {
    int cc2 = 3 * 64 + lane;
    if (cc2 < TOPK)
      kept[base + cc2] = ((kp3 >> lane) & 1ull) ? bscore[cc2] : 0.f;
  }
}

// ---------------------------------------------------------------------------
// Kernel 1 (fallback chain, proven): strided scan version for small ws_size
// ---------------------------------------------------------------------------
__global__ __launch_bounds__(256) void perclass_fallback(
    const float* __restrict__ loc, const float* __restrict__ conf,
    const float* __restrict__ prior, float* __restrict__ kept,
    float* __restrict__ cbox) {
  __shared__ u16 skey[NP];
  __shared__ unsigned int hist[256];
  __shared__ u64 keys[256];
  __shared__ float bx0[TOPK], bx1[TOPK], bx2[TOPK], bx3[TOPK];
  __shared__ float barea[TOPK], bscore[TOPK];
  __shared__ unsigned char sup[TOPK], keepf[TOPK];
  __shared__ unsigned int s_sel, s_rem, s_cnt, s_cnt2;

  const int tid = threadIdx.x;
  const int nwg = NB * NCLS;
  int i0 = blockIdx.x;
  int bc = (i0 & 7) * (nwg / 8) + (i0 >> 3);
  const int b = bc / NCLS, c = bc % NCLS;
  const size_t keptBase = (size_t)bc * TOPK;

  if (c == 0) {
    for (int k = tid; k < TOPK; k += 256) {
      kept[keptBase + k] = 0.f;
      float* bp = cbox + (keptBase + k) * 4;
      bp[0] = 0.f; bp[1] = 0.f; bp[2] = 0.f; bp[3] = 0.f;
    }
    return;
  }

  const float* confb = conf + (size_t)b * NP * NCLS + c;
  auto loadscore = [&](int p) -> float {
    float s = confb[(size_t)p * NCLS];
    return (s > CONF_THR) ? s : -1.0f;
  };

  for (int p = tid; p < NP; p += 256)
    skey[p] = (u16)(fkey(loadscore(p)) >> 16);
  __syncthreads();

  auto select_bin = [&](u32 Kin) {
    if (tid == 0) {
      u32 rem = Kin;
      int bin = 255;
      for (; bin > 0; --bin) {
        u32 cnt = hist[bin];
        if (cnt >= rem) break;
        rem -= cnt;
      }
      s_sel = (u32)bin; s_rem = rem;
    }
    __syncthreads();
  };

  const u32 NEGK16 = 0x407Fu;
  u32 K = TOPK;
  hist[tid] = 0; __syncthreads();
  for (int p = tid; p < NP; p += 256) atomicAdd(&hist[skey[p] >> 8], 1u);
  __syncthreads();
  select_bin(K);
  u32 pfx16 = s_sel << 8; K = s_rem;

  hist[tid] = 0; __syncthreads();
  {
    u32 hb = pfx16 >> 8;
    for (int p = tid; p < NP; p += 256) {
      u16 v = skey[p];
      if ((u32)(v >> 8) == hb) atomicAdd(&hist[v & 255], 1u);
    }
  }
  __syncthreads();
  select_bin(K);
  pfx16 |= s_sel; K = s_rem;

  const bool fillMode = (pfx16 == NEGK16);
  u32 T;
  if (!fillMode) {
    u32 pfull = pfx16 << 16;
    hist[tid] = 0; __syncthreads();
    for (int p = tid; p < NP; p += 256) {
      if ((u32)skey[p] == pfx16) {
        u32 kf = fkey(loadscore(p));
        atomicAdd(&hist[(kf >> 8) & 255], 1u);
      }
    }
    __syncthreads();
    select_bin(K);
    pfull |= s_sel << 8; K = s_rem;

    hist[tid] = 0; __syncthreads();
    for (int p = tid; p < NP; p += 256) {
      if ((u32)skey[p] == pfx16) {
        u32 kf = fkey(loadscore(p));
        if ((kf >> 8) == (pfull >> 8)) atomicAdd(&hist[kf & 255], 1u);
      }
    }
    __syncthreads();
    select_bin(K);
    T = pfull | s_sel; K = s_rem;
  } else {
    T = 0x407FFFFFu;
  }

  const u32 G = TOPK - K;
  keys[tid] = 0;
  if (tid == 0) { s_cnt = 0; s_cnt2 = 0; }
  __syncthreads();
  for (int p = tid; p < NP; p += 256) {
    u32 v = skey[p];
    if (v > pfx16) {
      float s = loadscore(p);
      u32 slot = atomicAdd(&s_cnt, 1u);
      keys[slot] = ((u64)fkey(s) << 32) | (u32)(~(u32)p);
    } else if (!fillMode && v == pfx16) {
      float s = loadscore(p);
      u32 kf = fkey(s);
      if (kf > T) {
        u32 slot = atomicAdd(&s_cnt, 1u);
        keys[slot] = ((u64)kf << 32) | (u32)(~(u32)p);
      } else if (kf == T) {
        u32 t2 = atomicAdd(&s_cnt2, 1u);
        u32 slot = G + t2;
        if (slot < 256u) keys[slot] = ((u64)kf << 32) | (u32)(~(u32)p);
      }
    }
  }
  __syncthreads();
  if (fillMode) {
    for (int k = (int)G + tid; k < TOPK; k += 256)
      keys[k] = ((u64)T << 32) | 0xFFFFFFFFull;
  }
  __syncthreads();

  for (u32 kk = 2; kk <= 256; kk <<= 1) {
    for (u32 j = kk >> 1; j > 0; j >>= 1) {
      u32 ixj = (u32)tid ^ j;
      if (ixj > (u32)tid) {
        u64 a = keys[tid], bb = keys[ixj];
        bool asc = (tid & kk) != 0;
        if (asc ? (a > bb) : (a < bb)) { keys[tid] = bb; keys[ixj] = a; }
      }
      __syncthreads();
    }
  }

  if (tid < TOPK) {
    u64 e = keys[tid];
    float s = unfkey((u32)(e >> 32));
    int p = (int)(~(u32)e);
    const float* lp = loc + ((size_t)b * NP + p) * 4;
    const float* pp = prior + (size_t)p * 4;
    const float* vp = prior + (size_t)NP * 4 + (size_t)p * 4;
    float p0 = pp[0], p1 = pp[1], p2 = pp[2], p3 = pp[3];
    float pw = p2 - p0, ph = p3 - p1;
    float pcx = (p0 + p2) * 0.5f, pcy = (p1 + p3) * 0.5f;
    float cx = vp[0] * lp[0] * pw + pcx;
    float cy = vp[1] * lp[1] * ph + pcy;
    float w = expf(vp[2] * lp[2]) * pw;
    float h = expf(vp[3] * lp[3]) * ph;
    float x0 = cx - w * 0.5f, y0 = cy - h * 0.5f;
    float x1 = cx + w * 0.5f, y1 = cy + h * 0.5f;
    bx0[tid] = x0; bx1[tid] = y0; bx2[tid] = x1; bx3[tid] = y1;
    barea[tid] = fmaxf(x1 - x0, 0.f) * fmaxf(y1 - y0, 0.f);
    bscore[tid] = s;
    sup[tid] = 0;
    keepf[tid] = 0;
  }
  __syncthreads();

  for (int i = 0; i < TOPK; ++i) {
    bool kept_i = (bscore[i] > CONF_THR) && (sup[i] == 0);
    __syncthreads();
    if (kept_i) {
      if (tid < TOPK) {
        float xx1 = fmaxf(bx0[i], bx0[tid]);
        float yy1 = fmaxf(bx1[i], bx1[tid]);
        float xx2 = fminf(bx2[i], bx2[tid]);
        float yy2 = fminf(bx3[i], bx3[tid]);
        float inter = fmaxf(xx2 - xx1, 0.f) * fmaxf(yy2 - yy1, 0.f);
        float uni = barea[i] + barea[tid] - inter;
        float iou = inter / fmaxf(uni, 1e-10f);
        if (iou > NMS_THR) sup[tid] = 1;
      }
      if (tid == 0) keepf[i] = 1;
    }
    __syncthreads();
  }

  if (tid < TOPK) {
    kept[keptBase + tid] = keepf[tid] ? bscore[tid] : 0.f;
    float* bp = cbox + (keptBase + tid) * 4;
    bp[0] = bx0[tid]; bp[1] = bx1[tid]; bp[2] = bx2[tid]; bp[3] = bx3[tid];
  }
}

// ---------------------------------------------------------------------------
// Kernel 2: per-batch top-200 with parallel select + skewed hist
// ---------------------------------------------------------------------------
__global__ __launch_bounds__(256) void final_topk(
    const float* __restrict__ kept, const float* __restrict__ cbox,
    float* __restrict__ out) {
  __shared__ u32 histm[4 * 257];
  __shared__ u32 ssuf[256];
  __shared__ u64 keys[256];
  __shared__ u32 s_sel, s_rem, s_cnt, s_cnt2;

  const int tid = threadIdx.x;
  const int b = blockIdx.x;
  const float* sc = kept + (size_t)b * NFLAT;
  const int sub4 = (tid & 3) * 257;

  auto select256s = [&](u32 Kin) {
    __syncthreads();
    u32 cntv = histm[tid] + histm[257 + tid] + histm[514 + tid] + histm[771 + tid];
    ssuf[tid] = cntv;
    __syncthreads();
    for (int d = 1; d < 256; d <<= 1) {
      u32 add = (tid + d < 256) ? ssuf[tid + d] : 0u;
      __syncthreads();
      ssuf[tid] += add;
      __syncthreads();
    }
    u32 s = ssuf[tid], above = s - cntv;
    if (s >= Kin && above < Kin) { s_sel = (u32)tid; s_rem = Kin - above; }
    __syncthreads();
  };

  u32 pfx = 0;
  u32 K = KEEPK;
  for (int shift = 24; shift >= 0; shift -= 8) {
    for (int j = tid; j < 4 * 257; j += 256) histm[j] = 0u;
    __syncthreads();
    u32 himask = (shift == 24) ? 0u : (0xFFFFFFFFu << (shift + 8));
    for (int p = tid; p < NFLAT; p += 256) {
      u32 kf = fkey(sc[p]);
      if ((kf & himask) == pfx) atomicAdd(&histm[sub4 + ((kf >> shift) & 255u)], 1u);
    }
    select256s(K);
    pfx |= s_sel << shift; K = s_rem;
  }

  const bool fill2 = (pfx == fkey(0.0f));
  const u32 G = KEEPK - K;
  keys[tid] = 0;
  if (tid == 0) { s_cnt = 0; s_cnt2 = 0; }
  __syncthreads();
  for (int p = tid; p < NFLAT; p += 256) {
    u32 kf = fkey(sc[p]);
    if (kf > pfx) {
      u32 slot = atomicAdd(&s_cnt, 1u);
      keys[slot] = ((u64)kf << 32) | (u32)(~(u32)p);
    } else if (!fill2 && kf == pfx) {
      u32 t2 = atomicAdd(&s_cnt2, 1u);
      u32 slot = G + t2;
      if (slot < 256u) keys[slot] = ((u64)kf << 32) | (u32)(~(u32)p);
    }
  }
  __syncthreads();
  if (fill2) {
    for (int k = (int)G + tid; k < KEEPK; k += 256)
      keys[k] = ((u64)pfx << 32) | 0xFFFFFFFFull;
  }
  __syncthreads();

  for (u32 kk = 2; kk <= 256; kk <<= 1) {
    for (u32 j = kk >> 1; j > 0; j >>= 1) {
      u32 ixj = (u32)tid ^ j;
      if (ixj > (u32)tid) {
        u64 a = keys[tid], bb = keys[ixj];
        bool asc = (tid & kk) != 0;
        if (asc ? (a > bb) : (a < bb)) { keys[tid] = bb; keys[ixj] = a; }
      }
      __syncthreads();
    }
  }

  if (tid < KEEPK) {
    u64 e = keys[tid];
    float s = unfkey((u32)(e >> 32));
    u32 fi = ~(u32)e;
    float r0 = 0.f, r1 = 0.f, r2 = 0.f, r3 = 0.f, r4 = 0.f, r5 = 0.f, r6 = 0.f;
    if (s > 0.f) {
      r0 = (float)b;
      r1 = (float)(fi / TOPK);
      r2 = s;
      const float* bp = cbox + ((size_t)b * NFLAT + fi) * 4;
      r3 = bp[0]; r4 = bp[1]; r5 = bp[2]; r6 = bp[3];
    }
    float* op = out + ((size_t)b * KEEPK + tid) * 7;
    op[0] = r0; op[1] = r1; op[2] = r2; op[3] = r3;
    op[4] = r4; op[5] = r5; op[6] = r6;
  }
}

extern "C" void kernel_launch(void* const* d_in, const int* in_sizes, int n_in,
                              void* d_out, int out_size, void* d_ws, size_t ws_size,
                              hipStream_t stream) {
  const float* loc = (const float*)d_in[0];
  const float* conf = (const float*)d_in[1];
  const float* prior = (const float*)d_in[2];
  float* out = (float*)d_out;

  float* kept = (float*)d_ws;                     // NBC*TOPK floats
  float* cbox = kept + (size_t)NBC * TOPK;        // NBC*TOPK*4 floats
  const size_t baseBytes = (size_t)NBC * TOPK * 5 * sizeof(float);       // 10.37 MB
  const size_t lcntBytes = (size_t)NB * NCHUNK * NCLS * sizeof(u32);     // 0.995 MB
  const size_t lcandBytes = (size_t)NB * NCHUNK * NCLS * LCAP * sizeof(u64); // 31.85 MB
  const size_t bscBytes = (size_t)NBC * TOPK * sizeof(float);            // 2.07 MB

  if (ws_size >= baseBytes + lcntBytes + lcandBytes + bscBytes) {
    u32* lcnt = (u32*)((char*)d_ws + baseBytes);
    u64* lcand = (u64*)((char*)d_ws + baseBytes + lcntBytes);
    float* bscoreg = (float*)((char*)d_ws + baseBytes + lcntBytes + lcandBytes);
    collect_cands<<<dim3(NB * NCHUNK), dim3(256), 0, stream>>>(conf, lcnt, lcand);
    perclass_sel<<<dim3(NGRP), dim3(256), 0, stream>>>(loc, conf, prior, lcnt,
                                                       lcand, bscoreg, cbox);
    nms_kernel<<<dim3(NBC), dim3(64), 0, stream>>>(cbox, bscoreg, kept);
  } else {
    perclass_fallback<<<dim3(NBC), dim3(256), 0, stream>>>(loc, conf, prior,
                                                           kept, cbox);
  }
  final_topk<<<dim3(NB), dim3(256), 0, stream>>>(kept, cbox, out);
}